// Round 11
// baseline (214.582 us; speedup 1.0000x reference)
//
#include <hip/hip_runtime.h>
#include <stdint.h>

#define N_BATCH 32
#define B_OBJ   36
#define D_DIM   2048
#define Q_DIM   1024

typedef __bf16 bf16x8 __attribute__((ext_vector_type(8)));
typedef float  f32x4  __attribute__((ext_vector_type(4)));

__device__ __forceinline__ uint16_t f2bf(float f) {
    uint32_t u = __builtin_bit_cast(uint32_t, f);
    uint32_t r = (u + 0x7FFFu + ((u >> 16) & 1u)) >> 16;   // RNE
    return (uint16_t)r;
}

__device__ __forceinline__ void gld_lds16(const void* g, void* l) {
    __builtin_amdgcn_global_load_lds(
        (const __attribute__((address_space(1))) uint32_t*)g,
        (__attribute__((address_space(3))) uint32_t*)l, 16, 0, 0);
}

// ---- transpose + fp32->bf16, 64x64 tiles, vectorized ----
__global__ __launch_bounds__(256) void transpose_all(
    const float* __restrict__ W1, const float* __restrict__ W2,
    const float* __restrict__ W3,
    uint16_t* __restrict__ W1t, uint16_t* __restrict__ W2t,
    uint16_t* __restrict__ W3t) {
    __shared__ float tile[64][65];
    int gy = blockIdx.y;
    const float* W; uint16_t* Wt; int K, k0;
    if (gy < 32)      { W = W1; Wt = W1t; K = 2048; k0 = gy * 64; }
    else if (gy < 64) { W = W2; Wt = W2t; K = 2048; k0 = (gy - 32) * 64; }
    else              { W = W3; Wt = W3t; K = 1024; k0 = (gy - 64) * 64; }
    int n0 = blockIdx.x * 64;
    int t = threadIdx.x;
    {
        int r = t >> 4, c = (t & 15) * 4;
#pragma unroll
        for (int p = 0; p < 4; ++p)
            *(float4*)&tile[r + p * 16][c] =
                *(const float4*)&W[(size_t)(k0 + r + p * 16) * 2048 + n0 + c];
    }
    __syncthreads();
    {
        int n = t >> 2, kb = (t & 3) * 16;
#pragma unroll
        for (int g4 = 0; g4 < 4; ++g4) {
            int k = kb + g4 * 4;
            ushort4 o;
            o.x = f2bf(tile[k][n]);     o.y = f2bf(tile[k + 1][n]);
            o.z = f2bf(tile[k + 2][n]); o.w = f2bf(tile[k + 3][n]);
            *(ushort4*)&Wt[(size_t)(n0 + n) * K + k0 + k] = o;
        }
    }
}

// ---- qe GEMM: qpart[z] = q @ W3 over K-chunk z (M=32, N=2048, split-K=4) ----
__global__ __launch_bounds__(256) void qk_gemm(
    const float* __restrict__ q,
    const uint16_t* __restrict__ W3t,
    float* __restrict__ qpart) {
    __shared__ __align__(16) uint16_t As[32][32];
    __shared__ __align__(16) uint16_t Bs[128][32];
    int t = threadIdx.x, lane = t & 63, wave = t >> 6;
    int l15 = lane & 15, quad = lane >> 4;
    int n0 = blockIdx.x * 128;
    int kbase = blockIdx.y * 256;
    f32x4 acc[2][2] = {};
    int ar = t >> 3, ac = (t & 7) * 4;
    int br = t >> 2, bk = (t & 3) * 8;

    for (int k0 = 0; k0 < 256; k0 += 32) {
        __syncthreads();
        float4 av = *(const float4*)&q[(size_t)ar * Q_DIM + kbase + k0 + ac];
        ushort4 a4;
        a4.x = f2bf(av.x); a4.y = f2bf(av.y); a4.z = f2bf(av.z); a4.w = f2bf(av.w);
        *(ushort4*)&As[ar][ac] = a4;
        *(uint4*)&Bs[br][bk]      = *(const uint4*)&W3t[(size_t)(n0 + br) * Q_DIM + kbase + k0 + bk];
        *(uint4*)&Bs[br + 64][bk] = *(const uint4*)&W3t[(size_t)(n0 + br + 64) * Q_DIM + kbase + k0 + bk];
        __syncthreads();
        bf16x8 af[2], bfr[2];
        af[0]  = *(const bf16x8*)&As[l15][quad * 8];
        af[1]  = *(const bf16x8*)&As[16 + l15][quad * 8];
        bfr[0] = *(const bf16x8*)&Bs[wave * 32 + l15][quad * 8];
        bfr[1] = *(const bf16x8*)&Bs[wave * 32 + 16 + l15][quad * 8];
#pragma unroll
        for (int i = 0; i < 2; ++i)
#pragma unroll
            for (int j = 0; j < 2; ++j)
                acc[i][j] = __builtin_amdgcn_mfma_f32_16x16x32_bf16(af[i], bfr[j], acc[i][j], 0, 0, 0);
    }
    float* dst = qpart + (size_t)blockIdx.y * 32 * D_DIM;
#pragma unroll
    for (int i = 0; i < 2; ++i)
#pragma unroll
        for (int j = 0; j < 2; ++j) {
            int n = n0 + wave * 32 + j * 16 + l15;
#pragma unroll
            for (int r = 0; r < 4; ++r)
                dst[(size_t)(i * 16 + quad * 4 + r) * D_DIM + n] = acc[i][j][r];
        }
}

// ---- fused: qe = relu(sum_z qpart + b3) (in regs); u[n,i,d] = bf16(v*qe) ----
// grid (4, N_BATCH), 128 threads; block owns a 512-float d-chunk of batch nb.
__global__ __launch_bounds__(128) void qe_make_u(
    const float* __restrict__ qpart, const float* __restrict__ b3,
    const float* __restrict__ v, uint16_t* __restrict__ u) {
    int nb = blockIdx.y;
    int d4 = blockIdx.x * 128 + threadIdx.x;          // float4 index in row (512/row)
    const float4* p = (const float4*)qpart;
    size_t base = (size_t)nb * 512 + d4;
    float4 s0 = p[base], s1 = p[16384 + base], s2 = p[32768 + base], s3 = p[49152 + base];
    float4 b = ((const float4*)b3)[d4];
    float4 qe;
    qe.x = fmaxf(s0.x + s1.x + s2.x + s3.x + b.x, 0.f);
    qe.y = fmaxf(s0.y + s1.y + s2.y + s3.y + b.y, 0.f);
    qe.z = fmaxf(s0.z + s1.z + s2.z + s3.z + b.z, 0.f);
    qe.w = fmaxf(s0.w + s1.w + s2.w + s3.w + b.w, 0.f);
    const float4* v4 = (const float4*)v;
    ushort4* u4 = (ushort4*)u;
    size_t rb = (size_t)nb * B_OBJ * 512 + d4;
#pragma unroll 4
    for (int i = 0; i < B_OBJ; ++i) {
        float4 vv = v4[rb + (size_t)i * 512];
        ushort4 o;
        o.x = f2bf(vv.x * qe.x);
        o.y = f2bf(vv.y * qe.y);
        o.z = f2bf(vv.z * qe.z);
        o.w = f2bf(vv.w * qe.w);
        u4[rb + (size_t)i * 512] = o;
    }
}

// ---- pair-batched GEMM: M=72 real (2 batches x 36) x N=128, K=2048, BK=128 ----
// A-in-LDS + B-DIRECT-GLOBAL split:
//  * B fragments are loaded straight from the n-major weight matrix into regs
//    (8 x dwordx4 per wave per step) -> LDS reads drop 160->96 KB/block-step,
//    DMA writes 50->18 KB, and LDS shrinks to 52 KB -> 2 blocks/CU
//    (launch_bounds(512,4)) restoring cross-block latency cover.
//  * A staged exact (72x128 bf16 row-major, granule-XOR swizzle, R10-proven),
//    depth-2 counted vmcnt: per step issue [B(k) 8 loads, STAGE_A(k+1)], then
//    wait vmcnt(L) -> retires stageA(k)+B(k), leaves stageA(k+1) flying.
//  * Waves 0-1 stage 3 regions (L=3), waves 2-7 stage 2 (L=2); per-wave waits.
// mode 0: pairsum epilogue -> x (bf16). mode 1: relu(+bias) -> out (f32).
__global__ __launch_bounds__(512, 4) void gemm_batch(
    const uint16_t* __restrict__ A,    // 1152 x 2048 bf16 (32 batches x 36 rows)
    const uint16_t* __restrict__ Bt,   // 2048 x 2048 bf16 (n-major)
    const float* __restrict__ bias,
    void* __restrict__ Cv,
    int mode) {
    // A buffers: 2 x (72 rows x 128 u16) = 2 x 9216 u16 = 36864 B.
    // Epilogue yt[96][132] f32 = 50688 B. Dynamic request = 53248 B.
    extern __shared__ __align__(16) uint16_t smem[];
    float* yt = (float*)smem;

    int t = threadIdx.x, lane = t & 63, wave = t >> 6;
    int l15 = lane & 15, quad = lane >> 4;
    int wr = wave >> 2, wc = wave & 3;         // wave: batch wr, cols wc*32
    int nbp = blockIdx.y;                      // batch pair: 2*nbp, 2*nbp+1
    int n0 = blockIdx.x * 128;
    const uint16_t* Ab = A + (size_t)nbp * 72 * D_DIM;   // exactly 72 real rows

    // A staging: 18 regions of 1KB (4 rows x 128 u16). Region r: rows r*4+
    // (lane>>4); stored granule (lane&15) holds global granule (lane&15)^(row&7).
    // r = wave + 8c; waves 0-1: c<3 (3 regions), waves 2-7: 2 regions.
    const uint16_t* gpa[3];
    int ra[3];
#pragma unroll
    for (int c = 0; c < 3; ++c) {
        int r = wave + 8 * c;
        int rr = (r < 18) ? r : 0;
        int row = rr * 4 + (lane >> 4);
        gpa[c] = Ab + (size_t)row * D_DIM + ((lane & 15) ^ (row & 7)) * 8;
        ra[c] = r;
    }
    int L = (wave < 2) ? 3 : 2;

    // B direct-global: per lane, 2 row base pointers (j=0,1)
    const uint16_t* bp[2];
#pragma unroll
    for (int j = 0; j < 2; ++j)
        bp[j] = Bt + (size_t)(n0 + wc * 32 + j * 16 + l15) * D_DIM + quad * 8;

    f32x4 acc[3][2] = {};
    int axor = (4 * wr + l15) & 7;   // A read swizzle: (row&7) for rows wr*36+i*16+l15

#define STAGE_A(kk, bi)                                              \
    {                                                                \
        _Pragma("unroll")                                            \
        for (int c = 0; c < 3; ++c)                                  \
            if (ra[c] < 18)                                          \
                gld_lds16(gpa[c] + (kk), smem + (bi) * 9216 + ra[c] * 512); \
    }
#define WAIT_L()                                                      \
    {                                                                 \
        if (wave < 2) asm volatile("s_waitcnt vmcnt(3)" ::: "memory");\
        else          asm volatile("s_waitcnt vmcnt(2)" ::: "memory");\
    }

    // prologue: stage A(0)
    STAGE_A(0, 0);

    for (int k = 0; k < 16; ++k) {
        int cur = k & 1;
        int k0 = k * 128;
        // issue B(k) fragment loads (oldest after stageA(k))
        uint4 breg[2][4];
#pragma unroll
        for (int j = 0; j < 2; ++j)
#pragma unroll
            for (int s = 0; s < 4; ++s)
                breg[j][s] = *(const uint4*)(bp[j] + k0 + s * 32);
        // issue next A stage (newest; stays in flight through compute)
        if (k < 15) {
            STAGE_A((k + 1) * 128, cur ^ 1);
            WAIT_L();                          // stageA(k)+B(k) retired
        } else {
            asm volatile("s_waitcnt vmcnt(0)" ::: "memory");
        }
        __builtin_amdgcn_s_barrier();          // A(k) visible to all waves
        const uint16_t* Asb = smem + cur * 9216;
#pragma unroll
        for (int s = 0; s < 4; ++s) {
            bf16x8 af[3];
#pragma unroll
            for (int i = 0; i < 3; ++i)
                af[i] = *(const bf16x8*)(Asb + (wr * 36 + i * 16 + l15) * 128 +
                                         ((4 * s + quad) ^ axor) * 8);
#pragma unroll
            for (int i = 0; i < 3; ++i)
#pragma unroll
                for (int j = 0; j < 2; ++j)
                    acc[i][j] = __builtin_amdgcn_mfma_f32_16x16x32_bf16(
                        af[i], __builtin_bit_cast(bf16x8, breg[j][s]), acc[i][j], 0, 0, 0);
        }
        if (k < 15) __builtin_amdgcn_s_barrier();   // done reading buf[cur]
    }
#undef STAGE_A
#undef WAIT_L

    if (mode == 0) {
        uint16_t* X = (uint16_t*)Cv;
        __syncthreads();   // all waves done with K-loop before smem reuse as yt
#pragma unroll
        for (int i = 0; i < 3; ++i)
#pragma unroll
            for (int j = 0; j < 2; ++j)
#pragma unroll
                for (int r = 0; r < 4; ++r)
                    yt[(wr * 48 + i * 16 + quad * 4 + r) * 132 + wc * 32 + j * 16 + l15] = acc[i][j][r];
        __syncthreads();
        int col = t & 127, sub = t >> 7;           // sub: 0..3
        int b = sub >> 1, half = sub & 1;          // batch-in-pair, row-half
        float bv = bias[n0 + col];
        float z[36];
#pragma unroll
        for (int j = 0; j < 36; ++j) z[j] = yt[(b * 48 + j) * 132 + col];
#pragma unroll
        for (int ii = 0; ii < 18; ++ii) {
            int i = half * 18 + ii;
            float zi = z[i] + bv;
            float s = 0.f;
#pragma unroll
            for (int j = 0; j < 36; ++j) s += fmaxf(zi + z[j], 0.f);
            X[(size_t)((nbp * 2 + b) * B_OBJ + i) * D_DIM + n0 + col] = f2bf(s);
        }
    } else {
        float* O = (float*)Cv;
#pragma unroll
        for (int i = 0; i < 3; ++i)
#pragma unroll
            for (int r = 0; r < 4; ++r) {
                int obj = i * 16 + quad * 4 + r;   // row within this wave's batch
                if (obj < B_OBJ) {
#pragma unroll
                    for (int j = 0; j < 2; ++j) {
                        int cc = n0 + wc * 32 + j * 16 + l15;
                        O[(size_t)((nbp * 2 + wr) * B_OBJ + obj) * D_DIM + cc] =
                            fmaxf(acc[i][j][r] + bias[cc], 0.f);
                    }
                }
            }
    }
}

extern "C" void kernel_launch(void* const* d_in, const int* in_sizes, int n_in,
                              void* d_out, int out_size, void* d_ws, size_t ws_size,
                              hipStream_t stream) {
    const float* v  = (const float*)d_in[0];
    const float* q  = (const float*)d_in[1];
    const float* W1 = (const float*)d_in[2];
    const float* b1 = (const float*)d_in[3];
    const float* W2 = (const float*)d_in[4];
    const float* b2 = (const float*)d_in[5];
    const float* W3 = (const float*)d_in[6];
    const float* b3 = (const float*)d_in[7];
    float* out = (float*)d_out;

    char* ws = (char*)d_ws;
    uint16_t* W1t   = (uint16_t*)(ws + 0);           // 8 MiB
    uint16_t* W2t   = (uint16_t*)(ws + 8388608);     // 8 MiB
    uint16_t* W3t   = (uint16_t*)(ws + 16777216);    // 4 MiB, dead after qk_gemm
    uint16_t* u     = (uint16_t*)(ws + 16777216);    // 4.5 MiB (overlays dead W3t)
    float*    qpart = (float*)   (ws + 21495808);    // 1 MiB (also pads u/x over-reads)
    uint16_t* x     = (uint16_t*)(ws + 22806528);    // 4.5 MiB (ends 27525120; ws pads over-reads)

    // 53248 B dynamic LDS (2 A-buffers + pairsum epilogue) -> 2 blocks/CU
    static bool attr_done = false;
    if (!attr_done) {
        (void)hipFuncSetAttribute((const void*)gemm_batch,
                                  hipFuncAttributeMaxDynamicSharedMemorySize, 53248);
        attr_done = true;
    }

    transpose_all<<<dim3(32, 80), 256, 0, stream>>>(W1, W2, W3, W1t, W2t, W3t);

    qk_gemm<<<dim3(16, 4), 256, 0, stream>>>(q, W3t, qpart);

    qe_make_u<<<dim3(4, N_BATCH), 128, 0, stream>>>(qpart, b3, v, u);

    // GEMM1 + fused pairsum -> x (bf16); 16 batch pairs
    gemm_batch<<<dim3(16, 16), 512, 53248, stream>>>(u, W1t, b1, x, 0);

    // GEMM2 + bias + relu -> out (f32)
    gemm_batch<<<dim3(16, 16), 512, 53248, stream>>>(x, W2t, b2, out, 1);
}

// Round 12
// 175.542 us; speedup vs baseline: 1.2224x; 1.2224x over previous
//
#include <hip/hip_runtime.h>
#include <stdint.h>

#define N_BATCH 32
#define B_OBJ   36
#define D_DIM   2048
#define Q_DIM   1024

typedef __bf16 bf16x8 __attribute__((ext_vector_type(8)));
typedef float  f32x4  __attribute__((ext_vector_type(4)));

__device__ __forceinline__ uint16_t f2bf(float f) {
    uint32_t u = __builtin_bit_cast(uint32_t, f);
    uint32_t r = (u + 0x7FFFu + ((u >> 16) & 1u)) >> 16;   // RNE
    return (uint16_t)r;
}

__device__ __forceinline__ void gld_lds16(const void* g, void* l) {
    __builtin_amdgcn_global_load_lds(
        (const __attribute__((address_space(1))) uint32_t*)g,
        (__attribute__((address_space(3))) uint32_t*)l, 16, 0, 0);
}

// ---- transpose + fp32->bf16, 64x64 tiles, vectorized ----
__global__ __launch_bounds__(256) void transpose_all(
    const float* __restrict__ W1, const float* __restrict__ W2,
    const float* __restrict__ W3,
    uint16_t* __restrict__ W1t, uint16_t* __restrict__ W2t,
    uint16_t* __restrict__ W3t) {
    __shared__ float tile[64][65];
    int gy = blockIdx.y;
    const float* W; uint16_t* Wt; int K, k0;
    if (gy < 32)      { W = W1; Wt = W1t; K = 2048; k0 = gy * 64; }
    else if (gy < 64) { W = W2; Wt = W2t; K = 2048; k0 = (gy - 32) * 64; }
    else              { W = W3; Wt = W3t; K = 1024; k0 = (gy - 64) * 64; }
    int n0 = blockIdx.x * 64;
    int t = threadIdx.x;
    {
        int r = t >> 4, c = (t & 15) * 4;
#pragma unroll
        for (int p = 0; p < 4; ++p)
            *(float4*)&tile[r + p * 16][c] =
                *(const float4*)&W[(size_t)(k0 + r + p * 16) * 2048 + n0 + c];
    }
    __syncthreads();
    {
        int n = t >> 2, kb = (t & 3) * 16;
#pragma unroll
        for (int g4 = 0; g4 < 4; ++g4) {
            int k = kb + g4 * 4;
            ushort4 o;
            o.x = f2bf(tile[k][n]);     o.y = f2bf(tile[k + 1][n]);
            o.z = f2bf(tile[k + 2][n]); o.w = f2bf(tile[k + 3][n]);
            *(ushort4*)&Wt[(size_t)(n0 + n) * K + k0 + k] = o;
        }
    }
}

// ---- qe GEMM: qpart[z] = q @ W3 over K-chunk z (M=32, N=2048, split-K=4) ----
__global__ __launch_bounds__(256) void qk_gemm(
    const float* __restrict__ q,
    const uint16_t* __restrict__ W3t,
    float* __restrict__ qpart) {
    __shared__ __align__(16) uint16_t As[32][32];
    __shared__ __align__(16) uint16_t Bs[128][32];
    int t = threadIdx.x, lane = t & 63, wave = t >> 6;
    int l15 = lane & 15, quad = lane >> 4;
    int n0 = blockIdx.x * 128;
    int kbase = blockIdx.y * 256;
    f32x4 acc[2][2] = {};
    int ar = t >> 3, ac = (t & 7) * 4;
    int br = t >> 2, bk = (t & 3) * 8;

    for (int k0 = 0; k0 < 256; k0 += 32) {
        __syncthreads();
        float4 av = *(const float4*)&q[(size_t)ar * Q_DIM + kbase + k0 + ac];
        ushort4 a4;
        a4.x = f2bf(av.x); a4.y = f2bf(av.y); a4.z = f2bf(av.z); a4.w = f2bf(av.w);
        *(ushort4*)&As[ar][ac] = a4;
        *(uint4*)&Bs[br][bk]      = *(const uint4*)&W3t[(size_t)(n0 + br) * Q_DIM + kbase + k0 + bk];
        *(uint4*)&Bs[br + 64][bk] = *(const uint4*)&W3t[(size_t)(n0 + br + 64) * Q_DIM + kbase + k0 + bk];
        __syncthreads();
        bf16x8 af[2], bfr[2];
        af[0]  = *(const bf16x8*)&As[l15][quad * 8];
        af[1]  = *(const bf16x8*)&As[16 + l15][quad * 8];
        bfr[0] = *(const bf16x8*)&Bs[wave * 32 + l15][quad * 8];
        bfr[1] = *(const bf16x8*)&Bs[wave * 32 + 16 + l15][quad * 8];
#pragma unroll
        for (int i = 0; i < 2; ++i)
#pragma unroll
            for (int j = 0; j < 2; ++j)
                acc[i][j] = __builtin_amdgcn_mfma_f32_16x16x32_bf16(af[i], bfr[j], acc[i][j], 0, 0, 0);
    }
    float* dst = qpart + (size_t)blockIdx.y * 32 * D_DIM;
#pragma unroll
    for (int i = 0; i < 2; ++i)
#pragma unroll
        for (int j = 0; j < 2; ++j) {
            int n = n0 + wave * 32 + j * 16 + l15;
#pragma unroll
            for (int r = 0; r < 4; ++r)
                dst[(size_t)(i * 16 + quad * 4 + r) * D_DIM + n] = acc[i][j][r];
        }
}

// ---- fused: qe = relu(sum_z qpart + b3) (in regs); u[n,i,d] = bf16(v*qe) ----
// grid (4, N_BATCH), 128 threads; block owns a 512-float d-chunk of batch nb.
__global__ __launch_bounds__(128) void qe_make_u(
    const float* __restrict__ qpart, const float* __restrict__ b3,
    const float* __restrict__ v, uint16_t* __restrict__ u) {
    int nb = blockIdx.y;
    int d4 = blockIdx.x * 128 + threadIdx.x;          // float4 index in row (512/row)
    const float4* p = (const float4*)qpart;
    size_t base = (size_t)nb * 512 + d4;
    float4 s0 = p[base], s1 = p[16384 + base], s2 = p[32768 + base], s3 = p[49152 + base];
    float4 b = ((const float4*)b3)[d4];
    float4 qe;
    qe.x = fmaxf(s0.x + s1.x + s2.x + s3.x + b.x, 0.f);
    qe.y = fmaxf(s0.y + s1.y + s2.y + s3.y + b.y, 0.f);
    qe.z = fmaxf(s0.z + s1.z + s2.z + s3.z + b.z, 0.f);
    qe.w = fmaxf(s0.w + s1.w + s2.w + s3.w + b.w, 0.f);
    const float4* v4 = (const float4*)v;
    ushort4* u4 = (ushort4*)u;
    size_t rb = (size_t)nb * B_OBJ * 512 + d4;
#pragma unroll 4
    for (int i = 0; i < B_OBJ; ++i) {
        float4 vv = v4[rb + (size_t)i * 512];
        ushort4 o;
        o.x = f2bf(vv.x * qe.x);
        o.y = f2bf(vv.y * qe.y);
        o.z = f2bf(vv.z * qe.z);
        o.w = f2bf(vv.w * qe.w);
        u4[rb + (size_t)i * 512] = o;
    }
}

// ---- pair-batched GEMM: M=72 real (2 batches x 36) x N=128, K=2048, BK=128 ----
// R9 cadence (depth-2 double buffer, 2 barriers/step, counted vmcnt) with the
// exact-72-row A layout (no junk-row staging; -11% A DMA, buffer 56->50 KB):
//  * A: 72 x 128 bf16 row-major, 18 regions of 4 rows x 128 u16; stored
//    granule (lane&15) holds global granule (lane&15)^(row&7) [XOR involution].
//  * B: [4 K-quarters][128 rows][32 u16], 32 regions, slot swizzle
//    (lane&3)^((lane>>2)&3) as before.
// 50 regions of 1KB/step: waves 0-1 issue 7 (vmcnt 7), waves 2-7 issue 6 (6).
// Wave reads A rows wr*36 + i*16 + l15; garbage positions (>=36 per half) land
// in-buffer (finite bf16) and are discarded by the epilogue row mapping.
// mode 0: pairsum epilogue -> x (bf16). mode 1: relu(+bias) -> out (f32).
__global__ __launch_bounds__(512) void gemm_batch(
    const uint16_t* __restrict__ A,    // 1152 x 2048 bf16 (32 batches x 36 rows)
    const uint16_t* __restrict__ Bt,   // 2048 x 2048 bf16 (n-major)
    const float* __restrict__ bias,
    void* __restrict__ Cv,
    int mode) {
    // Buffer: A 9216 u16 (18 KB) + B 16384 u16 (32 KB) = 25600 u16 = 51200 B; x2.
    // Epilogue reuses as yt[96][132] f32 = 50688 B (<= 102400).
    extern __shared__ __align__(16) uint16_t smem[];
    float* yt = (float*)smem;

    int t = threadIdx.x, lane = t & 63, wave = t >> 6;
    int l15 = lane & 15, quad = lane >> 4;
    int wr = wave >> 2, wc = wave & 3;         // wave: batch wr, cols wc*32
    int nbp = blockIdx.y;                      // batch pair: 2*nbp, 2*nbp+1
    int n0 = blockIdx.x * 128;
    const uint16_t* Ab = A + (size_t)nbp * 72 * D_DIM;   // exactly 72 real rows

    // 50 regions of 1KB, region r = wave + 8c (waves 0-1: c<7, waves 2-7: c<6):
    //  r<18:  A region: 4 rows x 128 u16. Lane -> row r*4+(lane>>4), stored
    //         granule (lane&15) holds global granule (lane&15)^(row&7).
    //  r>=18: B region rb=r-18: h=rb>>3 (K-quarter), g=rb&7 (rowgroup of 16).
    //         Lane -> row g*16+(lane>>2), slot (lane&3) holds (lane&3)^((lane>>2)&3).
    const uint16_t* gp[7];
    int loff[7];
    int wslot = (lane & 3) ^ ((lane >> 2) & 3);
#pragma unroll
    for (int c = 0; c < 7; ++c) {
        int r = wave + 8 * c;
        int rr = (r < 50) ? r : 0;
        if (rr < 18) {
            int row = rr * 4 + (lane >> 4);
            gp[c] = Ab + (size_t)row * D_DIM + ((lane & 15) ^ (row & 7)) * 8;
            loff[c] = rr * 512;
        } else {
            int rb = rr - 18, h = rb >> 3, g = rb & 7;
            int brow = g * 16 + (lane >> 2);
            gp[c] = Bt + (size_t)(n0 + brow) * D_DIM + h * 32 + wslot * 8;
            loff[c] = 9216 + h * 4096 + g * 512;
        }
    }

    f32x4 acc[3][2] = {};
    // read-side swizzles:
    int axor  = (4 * wr + l15) & 7;        // A: (row&7) for rows wr*36+i*16+l15
    int rslot = quad ^ (l15 & 3);          // B: same involution as staged

#define STAGE(kk, bi)                                            \
    {                                                            \
        _Pragma("unroll")                                        \
        for (int c = 0; c < 7; ++c)                              \
            if (wave + 8 * c < 50)                               \
                gld_lds16(gp[c] + (kk), smem + (bi) * 25600 + loff[c]); \
    }
#define WAIT_L()                                                      \
    {                                                                 \
        if (wave < 2) asm volatile("s_waitcnt vmcnt(7)" ::: "memory");\
        else          asm volatile("s_waitcnt vmcnt(6)" ::: "memory");\
    }

    // prologue: fill both buffers; wait for stage0 only (stage1 in flight)
    STAGE(0, 0);
    STAGE(128, 1);
    WAIT_L();
    __builtin_amdgcn_s_barrier();

    for (int k = 0; k < 16; ++k) {
        int cur = k & 1;
        const uint16_t* As = smem + cur * 25600;
        const uint16_t* Bs = As + 9216;
#pragma unroll
        for (int s = 0; s < 4; ++s) {
            bf16x8 af[3], bfr[2];
#pragma unroll
            for (int i = 0; i < 3; ++i)
                af[i] = *(const bf16x8*)(As + (wr * 36 + i * 16 + l15) * 128 +
                                         ((4 * s + quad) ^ axor) * 8);
#pragma unroll
            for (int j = 0; j < 2; ++j)
                bfr[j] = *(const bf16x8*)(Bs + s * 4096 +
                                          (wc * 32 + j * 16 + l15) * 32 + rslot * 8);
#pragma unroll
            for (int i = 0; i < 3; ++i)
#pragma unroll
                for (int j = 0; j < 2; ++j)
                    acc[i][j] = __builtin_amdgcn_mfma_f32_16x16x32_bf16(af[i], bfr[j], acc[i][j], 0, 0, 0);
        }
        if (k == 15) break;
        __builtin_amdgcn_s_barrier();              // all waves done reading buf[cur]
        if (k < 14) {
            STAGE((k + 2) * 128, cur);             // refill freed buffer
            WAIT_L();                              // stage k+1 retired; k+2 in flight
        } else {                                   // k == 14: drain stage 15
            asm volatile("s_waitcnt vmcnt(0)" ::: "memory");
        }
        __builtin_amdgcn_s_barrier();              // next buffer ready
    }
#undef STAGE
#undef WAIT_L

    if (mode == 0) {
        uint16_t* X = (uint16_t*)Cv;
        __syncthreads();   // all waves done with K-loop before smem reuse as yt
#pragma unroll
        for (int i = 0; i < 3; ++i)
#pragma unroll
            for (int j = 0; j < 2; ++j)
#pragma unroll
                for (int r = 0; r < 4; ++r)
                    yt[(wr * 48 + i * 16 + quad * 4 + r) * 132 + wc * 32 + j * 16 + l15] = acc[i][j][r];
        __syncthreads();
        int col = t & 127, sub = t >> 7;           // sub: 0..3
        int b = sub >> 1, half = sub & 1;          // batch-in-pair, row-half
        float bv = bias[n0 + col];
        float z[36];
#pragma unroll
        for (int j = 0; j < 36; ++j) z[j] = yt[(b * 48 + j) * 132 + col];
#pragma unroll
        for (int ii = 0; ii < 18; ++ii) {
            int i = half * 18 + ii;
            float zi = z[i] + bv;
            float s = 0.f;
#pragma unroll
            for (int j = 0; j < 36; ++j) s += fmaxf(zi + z[j], 0.f);
            X[(size_t)((nbp * 2 + b) * B_OBJ + i) * D_DIM + n0 + col] = f2bf(s);
        }
    } else {
        float* O = (float*)Cv;
#pragma unroll
        for (int i = 0; i < 3; ++i)
#pragma unroll
            for (int r = 0; r < 4; ++r) {
                int obj = i * 16 + quad * 4 + r;   // row within this wave's batch
                if (obj < B_OBJ) {
#pragma unroll
                    for (int j = 0; j < 2; ++j) {
                        int cc = n0 + wc * 32 + j * 16 + l15;
                        O[(size_t)((nbp * 2 + wr) * B_OBJ + obj) * D_DIM + cc] =
                            fmaxf(acc[i][j][r] + bias[cc], 0.f);
                    }
                }
            }
    }
}

extern "C" void kernel_launch(void* const* d_in, const int* in_sizes, int n_in,
                              void* d_out, int out_size, void* d_ws, size_t ws_size,
                              hipStream_t stream) {
    const float* v  = (const float*)d_in[0];
    const float* q  = (const float*)d_in[1];
    const float* W1 = (const float*)d_in[2];
    const float* b1 = (const float*)d_in[3];
    const float* W2 = (const float*)d_in[4];
    const float* b2 = (const float*)d_in[5];
    const float* W3 = (const float*)d_in[6];
    const float* b3 = (const float*)d_in[7];
    float* out = (float*)d_out;

    char* ws = (char*)d_ws;
    uint16_t* W1t   = (uint16_t*)(ws + 0);           // 8 MiB
    uint16_t* W2t   = (uint16_t*)(ws + 8388608);     // 8 MiB
    uint16_t* W3t   = (uint16_t*)(ws + 16777216);    // 4 MiB, dead after qk_gemm
    uint16_t* u     = (uint16_t*)(ws + 16777216);    // 4.5 MiB (overlays dead W3t)
    float*    qpart = (float*)   (ws + 21495808);    // 1 MiB
    uint16_t* x     = (uint16_t*)(ws + 22806528);    // 4.5 MiB (ends 27525120)

    // 102400 B dynamic LDS (2 x 51200 B buffers) — capture-safe host call
    static bool attr_done = false;
    if (!attr_done) {
        (void)hipFuncSetAttribute((const void*)gemm_batch,
                                  hipFuncAttributeMaxDynamicSharedMemorySize, 102400);
        attr_done = true;
    }

    transpose_all<<<dim3(32, 80), 256, 0, stream>>>(W1, W2, W3, W1t, W2t, W3t);

    qk_gemm<<<dim3(16, 4), 256, 0, stream>>>(q, W3t, qpart);

    qe_make_u<<<dim3(4, N_BATCH), 128, 0, stream>>>(qpart, b3, v, u);

    // GEMM1 + fused pairsum -> x (bf16); 16 batch pairs
    gemm_batch<<<dim3(16, 16), 512, 102400, stream>>>(u, W1t, b1, x, 0);

    // GEMM2 + bias + relu -> out (f32)
    gemm_batch<<<dim3(16, 16), 512, 102400, stream>>>(x, W2t, b2, out, 1);
}

// Round 13
// 164.338 us; speedup vs baseline: 1.3057x; 1.0682x over previous
//
#include <hip/hip_runtime.h>
#include <stdint.h>

#define N_BATCH 32
#define B_OBJ   36
#define D_DIM   2048
#define Q_DIM   1024

typedef __bf16 bf16x8 __attribute__((ext_vector_type(8)));
typedef float  f32x4  __attribute__((ext_vector_type(4)));

__device__ __forceinline__ uint16_t f2bf(float f) {
    uint32_t u = __builtin_bit_cast(uint32_t, f);
    uint32_t r = (u + 0x7FFFu + ((u >> 16) & 1u)) >> 16;   // RNE
    return (uint16_t)r;
}

__device__ __forceinline__ void gld_lds16(const void* g, void* l) {
    __builtin_amdgcn_global_load_lds(
        (const __attribute__((address_space(1))) uint32_t*)g,
        (__attribute__((address_space(3))) uint32_t*)l, 16, 0, 0);
}

// ---- transpose + fp32->bf16, 64x64 tiles, vectorized ----
__global__ __launch_bounds__(256) void transpose_all(
    const float* __restrict__ W1, const float* __restrict__ W2,
    const float* __restrict__ W3,
    uint16_t* __restrict__ W1t, uint16_t* __restrict__ W2t,
    uint16_t* __restrict__ W3t) {
    __shared__ float tile[64][65];
    int gy = blockIdx.y;
    const float* W; uint16_t* Wt; int K, k0;
    if (gy < 32)      { W = W1; Wt = W1t; K = 2048; k0 = gy * 64; }
    else if (gy < 64) { W = W2; Wt = W2t; K = 2048; k0 = (gy - 32) * 64; }
    else              { W = W3; Wt = W3t; K = 1024; k0 = (gy - 64) * 64; }
    int n0 = blockIdx.x * 64;
    int t = threadIdx.x;
    {
        int r = t >> 4, c = (t & 15) * 4;
#pragma unroll
        for (int p = 0; p < 4; ++p)
            *(float4*)&tile[r + p * 16][c] =
                *(const float4*)&W[(size_t)(k0 + r + p * 16) * 2048 + n0 + c];
    }
    __syncthreads();
    {
        int n = t >> 2, kb = (t & 3) * 16;
#pragma unroll
        for (int g4 = 0; g4 < 4; ++g4) {
            int k = kb + g4 * 4;
            ushort4 o;
            o.x = f2bf(tile[k][n]);     o.y = f2bf(tile[k + 1][n]);
            o.z = f2bf(tile[k + 2][n]); o.w = f2bf(tile[k + 3][n]);
            *(ushort4*)&Wt[(size_t)(n0 + n) * K + k0 + k] = o;
        }
    }
}

// ---- qe GEMM: qpart[z] = q @ W3 over K-chunk z (M=32, N=2048, split-K=4) ----
__global__ __launch_bounds__(256) void qk_gemm(
    const float* __restrict__ q,
    const uint16_t* __restrict__ W3t,
    float* __restrict__ qpart) {
    __shared__ __align__(16) uint16_t As[32][32];
    __shared__ __align__(16) uint16_t Bs[128][32];
    int t = threadIdx.x, lane = t & 63, wave = t >> 6;
    int l15 = lane & 15, quad = lane >> 4;
    int n0 = blockIdx.x * 128;
    int kbase = blockIdx.y * 256;
    f32x4 acc[2][2] = {};
    int ar = t >> 3, ac = (t & 7) * 4;
    int br = t >> 2, bk = (t & 3) * 8;

    for (int k0 = 0; k0 < 256; k0 += 32) {
        __syncthreads();
        float4 av = *(const float4*)&q[(size_t)ar * Q_DIM + kbase + k0 + ac];
        ushort4 a4;
        a4.x = f2bf(av.x); a4.y = f2bf(av.y); a4.z = f2bf(av.z); a4.w = f2bf(av.w);
        *(ushort4*)&As[ar][ac] = a4;
        *(uint4*)&Bs[br][bk]      = *(const uint4*)&W3t[(size_t)(n0 + br) * Q_DIM + kbase + k0 + bk];
        *(uint4*)&Bs[br + 64][bk] = *(const uint4*)&W3t[(size_t)(n0 + br + 64) * Q_DIM + kbase + k0 + bk];
        __syncthreads();
        bf16x8 af[2], bfr[2];
        af[0]  = *(const bf16x8*)&As[l15][quad * 8];
        af[1]  = *(const bf16x8*)&As[16 + l15][quad * 8];
        bfr[0] = *(const bf16x8*)&Bs[wave * 32 + l15][quad * 8];
        bfr[1] = *(const bf16x8*)&Bs[wave * 32 + 16 + l15][quad * 8];
#pragma unroll
        for (int i = 0; i < 2; ++i)
#pragma unroll
            for (int j = 0; j < 2; ++j)
                acc[i][j] = __builtin_amdgcn_mfma_f32_16x16x32_bf16(af[i], bfr[j], acc[i][j], 0, 0, 0);
    }
    float* dst = qpart + (size_t)blockIdx.y * 32 * D_DIM;
#pragma unroll
    for (int i = 0; i < 2; ++i)
#pragma unroll
        for (int j = 0; j < 2; ++j) {
            int n = n0 + wave * 32 + j * 16 + l15;
#pragma unroll
            for (int r = 0; r < 4; ++r)
                dst[(size_t)(i * 16 + quad * 4 + r) * D_DIM + n] = acc[i][j][r];
        }
}

// ---- fused: qe = relu(sum_z qpart + b3) (in regs); u = bf16(v*qe) ----
// grid (4, 6, N_BATCH), 128 threads: block = 512-float d-chunk x 6 objects.
// 768 blocks (3/CU) vs old 128 (0.5/CU): memory-bound op now has the wave
// count G11 asks for. qe recomputed per block (qpart re-read 6x, ~5 MB).
__global__ __launch_bounds__(128) void qe_make_u(
    const float* __restrict__ qpart, const float* __restrict__ b3,
    const float* __restrict__ v, uint16_t* __restrict__ u) {
    int nb = blockIdx.z;
    int og = blockIdx.y;                               // object group: 6 rows
    int d4 = blockIdx.x * 128 + threadIdx.x;           // float4 index in row
    const float4* p = (const float4*)qpart;
    size_t base = (size_t)nb * 512 + d4;
    float4 s0 = p[base], s1 = p[16384 + base], s2 = p[32768 + base], s3 = p[49152 + base];
    float4 b = ((const float4*)b3)[d4];
    float4 qe;
    qe.x = fmaxf(s0.x + s1.x + s2.x + s3.x + b.x, 0.f);
    qe.y = fmaxf(s0.y + s1.y + s2.y + s3.y + b.y, 0.f);
    qe.z = fmaxf(s0.z + s1.z + s2.z + s3.z + b.z, 0.f);
    qe.w = fmaxf(s0.w + s1.w + s2.w + s3.w + b.w, 0.f);
    const float4* v4 = (const float4*)v;
    ushort4* u4 = (ushort4*)u;
    size_t rb = (size_t)nb * B_OBJ * 512 + d4 + (size_t)og * 6 * 512;
#pragma unroll
    for (int i = 0; i < 6; ++i) {
        float4 vv = v4[rb + (size_t)i * 512];
        ushort4 o;
        o.x = f2bf(vv.x * qe.x);
        o.y = f2bf(vv.y * qe.y);
        o.z = f2bf(vv.z * qe.z);
        o.w = f2bf(vv.w * qe.w);
        u4[rb + (size_t)i * 512] = o;
    }
}

// ---- pair-batched GEMM: tile M=96 (2 batches x 48) x N=128, K=2048, BK=128 ----
// R9 verbatim (best measured: 168.3 us total). 16 K-steps, depth-2 counted
// vmcnt, 2 barriers/step, T2 slot swizzle, 56 uniform staging regions (7/wave).
// mode 0: pairsum epilogue -> x (bf16). mode 1: relu(+bias) -> out (f32).
__global__ __launch_bounds__(512) void gemm_batch(
    const uint16_t* __restrict__ A,    // 1152 x 2048 bf16 (32 batches x 36 rows)
    const uint16_t* __restrict__ Bt,   // 2048 x 2048 bf16 (n-major)
    const float* __restrict__ bias,
    void* __restrict__ Cv,
    int mode) {
    // Buffer: As = [4 q][96 rows][32 u16] = 12288 u16 (24 KB),
    //         Bs = [4 q][128][32] = 16384 u16 (32 KB) -> 28672 u16 = 57344 B; x2.
    // Epilogue reuses as yt[96][132] f32 = 50688 B.
    extern __shared__ __align__(16) uint16_t smem[];
    float* yt = (float*)smem;

    int t = threadIdx.x, lane = t & 63, wave = t >> 6;
    int l15 = lane & 15, quad = lane >> 4;
    int wr = wave >> 2, wc = wave & 3;         // wave tile: rows wr*48, cols wc*32
    int nbp = blockIdx.y;                      // batch pair: batches 2*nbp, 2*nbp+1
    int n0 = blockIdx.x * 128;
    const uint16_t* Ab = A + (size_t)nbp * 72 * D_DIM;   // 72 real rows per pair

    // 56 regions of 1KB, region r = wave + 8c (c = 0..6, uniform 7/wave):
    //  r<24:  A: g=r>>2 (row group g*16 of 96), h=r&3 (K-quarter of 128).
    //         LDS rows 0-47 = batch0 (36 real + 12 junk), 48-95 = batch1
    //         (real arow = ldsrow-12; junk rows read in-workspace, discarded).
    //  r>=24: B: rb=r-24: g=rb>>2 (row group of 128), h=rb&3.
    // Region = 16 rows x 32 u16; lane -> row lane>>2, swizzled 16B slot.
    const uint16_t* gp[7];
    int loff[7];
    int wslot = (lane & 3) ^ ((lane >> 2) & 3);
#pragma unroll
    for (int c = 0; c < 7; ++c) {
        int r = wave + 8 * c;
        if (r < 24) {
            int g = r >> 2, h = r & 3;
            int arow = g * 16 + (lane >> 2) - (g >= 3 ? 12 : 0);
            gp[c] = Ab + (size_t)arow * D_DIM + h * 32 + wslot * 8;
            loff[c] = h * 3072 + g * 512;
        } else {
            int rb = r - 24, g = rb >> 2, h = rb & 3;
            int brow = g * 16 + (lane >> 2);
            gp[c] = Bt + (size_t)(n0 + brow) * D_DIM + h * 32 + wslot * 8;
            loff[c] = 12288 + h * 4096 + g * 512;
        }
    }

    f32x4 acc[3][2] = {};
    // read-side swizzled slot: all rows this lane reads have row&3 == l15&3
    int rslot = quad ^ (l15 & 3);

#define STAGE(kk, bi)                                            \
    {                                                            \
        _Pragma("unroll")                                        \
        for (int c = 0; c < 7; ++c)                              \
            gld_lds16(gp[c] + (kk), smem + (bi) * 28672 + loff[c]); \
    }

    // prologue: fill both buffers; wait for stage0 only (stage1's 7 in flight)
    STAGE(0, 0);
    STAGE(128, 1);
    asm volatile("s_waitcnt vmcnt(7)" ::: "memory");
    __builtin_amdgcn_s_barrier();

    for (int k = 0; k < 16; ++k) {
        int cur = k & 1;
        const uint16_t* As = smem + cur * 28672;
        const uint16_t* Bs = As + 12288;
#pragma unroll
        for (int s = 0; s < 4; ++s) {
            bf16x8 af[3], bfr[2];
#pragma unroll
            for (int i = 0; i < 3; ++i)
                af[i] = *(const bf16x8*)(As + s * 3072 + (wr * 48 + i * 16 + l15) * 32 + rslot * 8);
#pragma unroll
            for (int j = 0; j < 2; ++j)
                bfr[j] = *(const bf16x8*)(Bs + s * 4096 + (wc * 32 + j * 16 + l15) * 32 + rslot * 8);
#pragma unroll
            for (int i = 0; i < 3; ++i)
#pragma unroll
                for (int j = 0; j < 2; ++j)
                    acc[i][j] = __builtin_amdgcn_mfma_f32_16x16x32_bf16(af[i], bfr[j], acc[i][j], 0, 0, 0);
        }
        if (k == 15) break;
        __builtin_amdgcn_s_barrier();              // all waves done reading buf[cur]
        if (k < 14) {
            STAGE((k + 2) * 128, cur);             // refill freed buffer
            asm volatile("s_waitcnt vmcnt(7)" ::: "memory");  // stage k+1 retired
        } else {                                   // k == 14: drain stage 15
            asm volatile("s_waitcnt vmcnt(0)" ::: "memory");
        }
        __builtin_amdgcn_s_barrier();              // next buffer ready
    }
#undef STAGE

    if (mode == 0) {
        uint16_t* X = (uint16_t*)Cv;
        __syncthreads();   // all waves done with K-loop before smem reuse as yt
#pragma unroll
        for (int i = 0; i < 3; ++i)
#pragma unroll
            for (int j = 0; j < 2; ++j)
#pragma unroll
                for (int r = 0; r < 4; ++r)
                    yt[(wr * 48 + i * 16 + quad * 4 + r) * 132 + wc * 32 + j * 16 + l15] = acc[i][j][r];
        __syncthreads();
        int col = t & 127, sub = t >> 7;           // sub: 0..3
        int b = sub >> 1, half = sub & 1;          // batch-in-pair, row-half
        float bv = bias[n0 + col];
        float z[36];
#pragma unroll
        for (int j = 0; j < 36; ++j) z[j] = yt[(b * 48 + j) * 132 + col];
#pragma unroll
        for (int ii = 0; ii < 18; ++ii) {
            int i = half * 18 + ii;
            float zi = z[i] + bv;
            float s = 0.f;
#pragma unroll
            for (int j = 0; j < 36; ++j) s += fmaxf(zi + z[j], 0.f);
            X[(size_t)((nbp * 2 + b) * B_OBJ + i) * D_DIM + n0 + col] = f2bf(s);
        }
    } else {
        float* O = (float*)Cv;
#pragma unroll
        for (int i = 0; i < 3; ++i)
#pragma unroll
            for (int r = 0; r < 4; ++r) {
                int obj = i * 16 + quad * 4 + r;   // row within this wave's batch
                if (obj < B_OBJ) {
#pragma unroll
                    for (int j = 0; j < 2; ++j) {
                        int cc = n0 + wc * 32 + j * 16 + l15;
                        O[(size_t)((nbp * 2 + wr) * B_OBJ + obj) * D_DIM + cc] =
                            fmaxf(acc[i][j][r] + bias[cc], 0.f);
                    }
                }
            }
    }
}

extern "C" void kernel_launch(void* const* d_in, const int* in_sizes, int n_in,
                              void* d_out, int out_size, void* d_ws, size_t ws_size,
                              hipStream_t stream) {
    const float* v  = (const float*)d_in[0];
    const float* q  = (const float*)d_in[1];
    const float* W1 = (const float*)d_in[2];
    const float* b1 = (const float*)d_in[3];
    const float* W2 = (const float*)d_in[4];
    const float* b2 = (const float*)d_in[5];
    const float* W3 = (const float*)d_in[6];
    const float* b3 = (const float*)d_in[7];
    float* out = (float*)d_out;

    char* ws = (char*)d_ws;
    uint16_t* W1t   = (uint16_t*)(ws + 0);           // 8 MiB
    uint16_t* W2t   = (uint16_t*)(ws + 8388608);     // 8 MiB
    uint16_t* W3t   = (uint16_t*)(ws + 16777216);    // 4 MiB, dead after qk_gemm
    uint16_t* u     = (uint16_t*)(ws + 16777216);    // 4.5 MiB (overlays dead W3t)
    float*    qpart = (float*)   (ws + 21495808);    // 1 MiB (also pads u over-reads)
    uint16_t* x     = (uint16_t*)(ws + 22806528);    // 4.5 MiB (ends 27525120; ws pads over-reads)

    // allow 114688 B of dynamic LDS for the BK=128 double buffer (capture-safe)
    static bool attr_done = false;
    if (!attr_done) {
        (void)hipFuncSetAttribute((const void*)gemm_batch,
                                  hipFuncAttributeMaxDynamicSharedMemorySize, 114688);
        attr_done = true;
    }

    transpose_all<<<dim3(32, 80), 256, 0, stream>>>(W1, W2, W3, W1t, W2t, W3t);

    qk_gemm<<<dim3(16, 4), 256, 0, stream>>>(q, W3t, qpart);

    qe_make_u<<<dim3(4, 6, N_BATCH), 128, 0, stream>>>(qpart, b3, v, u);

    // GEMM1 + fused pairsum -> x (bf16); 16 batch pairs
    gemm_batch<<<dim3(16, 16), 512, 114688, stream>>>(u, W1t, b1, x, 0);

    // GEMM2 + bias + relu -> out (f32)
    gemm_batch<<<dim3(16, 16), 512, 114688, stream>>>(x, W2t, b2, out, 1);
}

// Round 14
// 160.787 us; speedup vs baseline: 1.3346x; 1.0221x over previous
//
#include <hip/hip_runtime.h>
#include <stdint.h>

#define N_BATCH 32
#define B_OBJ   36
#define D_DIM   2048
#define Q_DIM   1024

typedef __bf16 bf16x8 __attribute__((ext_vector_type(8)));
typedef float  f32x4  __attribute__((ext_vector_type(4)));
typedef uint16_t u16x8 __attribute__((ext_vector_type(8)));

__device__ __forceinline__ uint16_t f2bf(float f) {
    uint32_t u = __builtin_bit_cast(uint32_t, f);
    uint32_t r = (u + 0x7FFFu + ((u >> 16) & 1u)) >> 16;   // RNE
    return (uint16_t)r;
}

__device__ __forceinline__ void gld_lds16(const void* g, void* l) {
    __builtin_amdgcn_global_load_lds(
        (const __attribute__((address_space(1))) uint32_t*)g,
        (__attribute__((address_space(3))) uint32_t*)l, 16, 0, 0);
}

// ---- transpose + fp32->bf16, 64x64 tiles: W1, W2 only (W3 folded into qk) ----
__global__ __launch_bounds__(256) void transpose_all(
    const float* __restrict__ W1, const float* __restrict__ W2,
    uint16_t* __restrict__ W1t, uint16_t* __restrict__ W2t) {
    __shared__ float tile[64][65];
    int gy = blockIdx.y;
    const float* W; uint16_t* Wt; int k0;
    if (gy < 32) { W = W1; Wt = W1t; k0 = gy * 64; }
    else         { W = W2; Wt = W2t; k0 = (gy - 32) * 64; }
    int n0 = blockIdx.x * 64;
    int t = threadIdx.x;
    {
        int r = t >> 4, c = (t & 15) * 4;
#pragma unroll
        for (int p = 0; p < 4; ++p)
            *(float4*)&tile[r + p * 16][c] =
                *(const float4*)&W[(size_t)(k0 + r + p * 16) * 2048 + n0 + c];
    }
    __syncthreads();
    {
        int n = t >> 2, kb = (t & 3) * 16;
#pragma unroll
        for (int g4 = 0; g4 < 4; ++g4) {
            int k = kb + g4 * 4;
            ushort4 o;
            o.x = f2bf(tile[k][n]);     o.y = f2bf(tile[k + 1][n]);
            o.z = f2bf(tile[k + 2][n]); o.w = f2bf(tile[k + 3][n]);
            *(ushort4*)&Wt[(size_t)(n0 + n) * 2048 + k0 + k] = o;
        }
    }
}

// ---- qe GEMM v2: qpart[z] = q @ W3 chunk z; W3 read k-major f32 directly
// (transpose folded into staging — each W3 element touched by exactly one
// block). split-K=16 (grid 16x16 = 256 blocks, 4x the old occupancy).
__global__ __launch_bounds__(256) void qk_gemm(
    const float* __restrict__ q,
    const float* __restrict__ W3,
    float* __restrict__ qpart) {
    __shared__ __align__(16) uint16_t As[32][32];
    __shared__ __align__(16) float tile[32][132];   // k-major f32 stage, padded
    int t = threadIdx.x, lane = t & 63, wave = t >> 6;
    int l15 = lane & 15, quad = lane >> 4;
    int n0 = blockIdx.x * 128;
    int kbase = blockIdx.y * 64;
    f32x4 acc[2][2] = {};
    int ar = t >> 3, ac = (t & 7) * 4;
    int kr = t >> 3, nc = (t & 7) * 16;

    for (int k0 = 0; k0 < 64; k0 += 32) {
        __syncthreads();
        // A: q rows, f32->bf16
        float4 av = *(const float4*)&q[(size_t)ar * Q_DIM + kbase + k0 + ac];
        ushort4 a4;
        a4.x = f2bf(av.x); a4.y = f2bf(av.y); a4.z = f2bf(av.z); a4.w = f2bf(av.w);
        *(ushort4*)&As[ar][ac] = a4;
        // B: stage k-major W3 rows (coalesced float4)
        const float* wrow = &W3[(size_t)(kbase + k0 + kr) * 2048 + n0 + nc];
#pragma unroll
        for (int g = 0; g < 4; ++g)
            *(float4*)&tile[kr][nc + g * 4] = *(const float4*)(wrow + g * 4);
        __syncthreads();
        bf16x8 af[2], bfr[2];
        af[0] = *(const bf16x8*)&As[l15][quad * 8];
        af[1] = *(const bf16x8*)&As[16 + l15][quad * 8];
#pragma unroll
        for (int j = 0; j < 2; ++j) {
            int n = wave * 32 + j * 16 + l15;
            u16x8 pk;
#pragma unroll
            for (int e = 0; e < 8; ++e)
                pk[e] = f2bf(tile[quad * 8 + e][n]);   // transposed read + cvt
            bfr[j] = __builtin_bit_cast(bf16x8, pk);
        }
#pragma unroll
        for (int i = 0; i < 2; ++i)
#pragma unroll
            for (int j = 0; j < 2; ++j)
                acc[i][j] = __builtin_amdgcn_mfma_f32_16x16x32_bf16(af[i], bfr[j], acc[i][j], 0, 0, 0);
    }
    float* dst = qpart + (size_t)blockIdx.y * 32 * D_DIM;
#pragma unroll
    for (int i = 0; i < 2; ++i)
#pragma unroll
        for (int j = 0; j < 2; ++j) {
            int n = n0 + wave * 32 + j * 16 + l15;
#pragma unroll
            for (int r = 0; r < 4; ++r)
                dst[(size_t)(i * 16 + quad * 4 + r) * D_DIM + n] = acc[i][j][r];
        }
}

// ---- fused: qe = relu(sum_{z<16} qpart + b3) (in regs); u = bf16(v*qe) ----
// grid (4, 6, N_BATCH), 128 threads: block = 512-float d-chunk x 6 objects.
__global__ __launch_bounds__(128) void qe_make_u(
    const float* __restrict__ qpart, const float* __restrict__ b3,
    const float* __restrict__ v, uint16_t* __restrict__ u) {
    int nb = blockIdx.z;
    int og = blockIdx.y;                               // object group: 6 rows
    int d4 = blockIdx.x * 128 + threadIdx.x;           // float4 index in row
    const float4* p = (const float4*)qpart;
    size_t base = (size_t)nb * 512 + d4;
    float4 a = ((const float4*)b3)[d4];
#pragma unroll
    for (int z = 0; z < 16; ++z) {
        float4 s = p[(size_t)z * 16384 + base];
        a.x += s.x; a.y += s.y; a.z += s.z; a.w += s.w;
    }
    float4 qe;
    qe.x = fmaxf(a.x, 0.f); qe.y = fmaxf(a.y, 0.f);
    qe.z = fmaxf(a.z, 0.f); qe.w = fmaxf(a.w, 0.f);
    const float4* v4 = (const float4*)v;
    ushort4* u4 = (ushort4*)u;
    size_t rb = (size_t)nb * B_OBJ * 512 + d4 + (size_t)og * 6 * 512;
#pragma unroll
    for (int i = 0; i < 6; ++i) {
        float4 vv = v4[rb + (size_t)i * 512];
        ushort4 o;
        o.x = f2bf(vv.x * qe.x);
        o.y = f2bf(vv.y * qe.y);
        o.z = f2bf(vv.z * qe.z);
        o.w = f2bf(vv.w * qe.w);
        u4[rb + (size_t)i * 512] = o;
    }
}

// ---- pair-batched GEMM: tile M=96 (2 batches x 48) x N=128, K=2048, BK=128 ----
// R9/R13 verbatim (best measured). 16 K-steps, depth-2 counted vmcnt,
// 2 barriers/step, T2 slot swizzle, 56 uniform staging regions (7/wave).
// mode 0: pairsum epilogue -> x (bf16). mode 1: relu(+bias) -> out (f32).
__global__ __launch_bounds__(512) void gemm_batch(
    const uint16_t* __restrict__ A,    // 1152 x 2048 bf16 (32 batches x 36 rows)
    const uint16_t* __restrict__ Bt,   // 2048 x 2048 bf16 (n-major)
    const float* __restrict__ bias,
    void* __restrict__ Cv,
    int mode) {
    // Buffer: As = [4 q][96 rows][32 u16] (24 KB) + Bs = [4 q][128][32] (32 KB)
    // = 57344 B; x2. Epilogue reuses as yt[96][132] f32 = 50688 B.
    extern __shared__ __align__(16) uint16_t smem[];
    float* yt = (float*)smem;

    int t = threadIdx.x, lane = t & 63, wave = t >> 6;
    int l15 = lane & 15, quad = lane >> 4;
    int wr = wave >> 2, wc = wave & 3;         // wave tile: rows wr*48, cols wc*32
    int nbp = blockIdx.y;                      // batch pair: batches 2*nbp, 2*nbp+1
    int n0 = blockIdx.x * 128;
    const uint16_t* Ab = A + (size_t)nbp * 72 * D_DIM;   // 72 real rows per pair

    // 56 regions of 1KB, region r = wave + 8c (c = 0..6, uniform 7/wave):
    //  r<24:  A: g=r>>2 (row group g*16 of 96), h=r&3 (K-quarter of 128).
    //         LDS rows 0-47 = batch0 (36 real + 12 junk), 48-95 = batch1
    //         (real arow = ldsrow-12; junk rows read in-workspace, discarded).
    //  r>=24: B: rb=r-24: g=rb>>2 (row group of 128), h=rb&3.
    // Region = 16 rows x 32 u16; lane -> row lane>>2, swizzled 16B slot.
    const uint16_t* gp[7];
    int loff[7];
    int wslot = (lane & 3) ^ ((lane >> 2) & 3);
#pragma unroll
    for (int c = 0; c < 7; ++c) {
        int r = wave + 8 * c;
        if (r < 24) {
            int g = r >> 2, h = r & 3;
            int arow = g * 16 + (lane >> 2) - (g >= 3 ? 12 : 0);
            gp[c] = Ab + (size_t)arow * D_DIM + h * 32 + wslot * 8;
            loff[c] = h * 3072 + g * 512;
        } else {
            int rb = r - 24, g = rb >> 2, h = rb & 3;
            int brow = g * 16 + (lane >> 2);
            gp[c] = Bt + (size_t)(n0 + brow) * D_DIM + h * 32 + wslot * 8;
            loff[c] = 12288 + h * 4096 + g * 512;
        }
    }

    f32x4 acc[3][2] = {};
    // read-side swizzled slot: all rows this lane reads have row&3 == l15&3
    int rslot = quad ^ (l15 & 3);

#define STAGE(kk, bi)                                            \
    {                                                            \
        _Pragma("unroll")                                        \
        for (int c = 0; c < 7; ++c)                              \
            gld_lds16(gp[c] + (kk), smem + (bi) * 28672 + loff[c]); \
    }

    // prologue: fill both buffers; wait for stage0 only (stage1's 7 in flight)
    STAGE(0, 0);
    STAGE(128, 1);
    asm volatile("s_waitcnt vmcnt(7)" ::: "memory");
    __builtin_amdgcn_s_barrier();

    for (int k = 0; k < 16; ++k) {
        int cur = k & 1;
        const uint16_t* As = smem + cur * 28672;
        const uint16_t* Bs = As + 12288;
#pragma unroll
        for (int s = 0; s < 4; ++s) {
            bf16x8 af[3], bfr[2];
#pragma unroll
            for (int i = 0; i < 3; ++i)
                af[i] = *(const bf16x8*)(As + s * 3072 + (wr * 48 + i * 16 + l15) * 32 + rslot * 8);
#pragma unroll
            for (int j = 0; j < 2; ++j)
                bfr[j] = *(const bf16x8*)(Bs + s * 4096 + (wc * 32 + j * 16 + l15) * 32 + rslot * 8);
#pragma unroll
            for (int i = 0; i < 3; ++i)
#pragma unroll
                for (int j = 0; j < 2; ++j)
                    acc[i][j] = __builtin_amdgcn_mfma_f32_16x16x32_bf16(af[i], bfr[j], acc[i][j], 0, 0, 0);
        }
        if (k == 15) break;
        __builtin_amdgcn_s_barrier();              // all waves done reading buf[cur]
        if (k < 14) {
            STAGE((k + 2) * 128, cur);             // refill freed buffer
            asm volatile("s_waitcnt vmcnt(7)" ::: "memory");  // stage k+1 retired
        } else {                                   // k == 14: drain stage 15
            asm volatile("s_waitcnt vmcnt(0)" ::: "memory");
        }
        __builtin_amdgcn_s_barrier();              // next buffer ready
    }
#undef STAGE

    if (mode == 0) {
        uint16_t* X = (uint16_t*)Cv;
        __syncthreads();   // all waves done with K-loop before smem reuse as yt
#pragma unroll
        for (int i = 0; i < 3; ++i)
#pragma unroll
            for (int j = 0; j < 2; ++j)
#pragma unroll
                for (int r = 0; r < 4; ++r)
                    yt[(wr * 48 + i * 16 + quad * 4 + r) * 132 + wc * 32 + j * 16 + l15] = acc[i][j][r];
        __syncthreads();
        int col = t & 127, sub = t >> 7;           // sub: 0..3
        int b = sub >> 1, half = sub & 1;          // batch-in-pair, row-half
        float bv = bias[n0 + col];
        float z[36];
#pragma unroll
        for (int j = 0; j < 36; ++j) z[j] = yt[(b * 48 + j) * 132 + col];
#pragma unroll
        for (int ii = 0; ii < 18; ++ii) {
            int i = half * 18 + ii;
            float zi = z[i] + bv;
            float s = 0.f;
#pragma unroll
            for (int j = 0; j < 36; ++j) s += fmaxf(zi + z[j], 0.f);
            X[(size_t)((nbp * 2 + b) * B_OBJ + i) * D_DIM + n0 + col] = f2bf(s);
        }
    } else {
        float* O = (float*)Cv;
#pragma unroll
        for (int i = 0; i < 3; ++i)
#pragma unroll
            for (int r = 0; r < 4; ++r) {
                int obj = i * 16 + quad * 4 + r;   // row within this wave's batch
                if (obj < B_OBJ) {
#pragma unroll
                    for (int j = 0; j < 2; ++j) {
                        int cc = n0 + wc * 32 + j * 16 + l15;
                        O[(size_t)((nbp * 2 + wr) * B_OBJ + obj) * D_DIM + cc] =
                            fmaxf(acc[i][j][r] + bias[cc], 0.f);
                    }
                }
            }
    }
}

extern "C" void kernel_launch(void* const* d_in, const int* in_sizes, int n_in,
                              void* d_out, int out_size, void* d_ws, size_t ws_size,
                              hipStream_t stream) {
    const float* v  = (const float*)d_in[0];
    const float* q  = (const float*)d_in[1];
    const float* W1 = (const float*)d_in[2];
    const float* b1 = (const float*)d_in[3];
    const float* W2 = (const float*)d_in[4];
    const float* b2 = (const float*)d_in[5];
    const float* W3 = (const float*)d_in[6];
    const float* b3 = (const float*)d_in[7];
    float* out = (float*)d_out;

    char* ws = (char*)d_ws;
    uint16_t* W1t   = (uint16_t*)(ws + 0);           // 8 MiB
    uint16_t* W2t   = (uint16_t*)(ws + 8388608);     // 8 MiB
    uint16_t* u     = (uint16_t*)(ws + 16777216);    // 4.5 MiB (ends 21495808)
    float*    qpart = (float*)   (ws + 21495808);    // 4 MiB, 16 slices (ends 25690112)
    uint16_t* x     = (uint16_t*)(ws + 25690112);    // 4.5 MiB (ends 30408704)
    // gemm junk-row over-reads: u+4.77MB lands in qpart; x+4.77MB < ws end. Safe.

    // allow 114688 B of dynamic LDS for the BK=128 double buffer (capture-safe)
    static bool attr_done = false;
    if (!attr_done) {
        (void)hipFuncSetAttribute((const void*)gemm_batch,
                                  hipFuncAttributeMaxDynamicSharedMemorySize, 114688);
        attr_done = true;
    }

    // W1, W2 transpose only (W3 handled inside qk_gemm)
    transpose_all<<<dim3(32, 64), 256, 0, stream>>>(W1, W2, W1t, W2t);

    // split-K=16 qk GEMM reading W3 k-major f32 directly
    qk_gemm<<<dim3(16, 16), 256, 0, stream>>>(q, W3, qpart);

    qe_make_u<<<dim3(4, 6, N_BATCH), 128, 0, stream>>>(qpart, b3, v, u);

    // GEMM1 + fused pairsum -> x (bf16); 16 batch pairs
    gemm_batch<<<dim3(16, 16), 512, 114688, stream>>>(u, W1t, b1, x, 0);

    // GEMM2 + bias + relu -> out (f32)
    gemm_batch<<<dim3(16, 16), 512, 114688, stream>>>(x, W2t, b2, out, 1);
}